// Round 8
// baseline (526.052 us; speedup 1.0000x reference)
//
#include <hip/hip_runtime.h>
#include <math.h>

#define NNT 48
#define LL 32
#define BB 32
#define N2 2304            // 48*48
#define KSTEPS 72          // 2304/32
#define EPSV 1e-30f
#define CH_J ((LL+1)*NNT)  // 1584: chart stride of the row index
#define SEB_S 2328         // shorts per sEb row (2304 + pad)
#define PD_NT 264          // floats per nt-tile in pD
#define PD_S  (3*PD_NT)    // 792

typedef __attribute__((ext_vector_type(8))) short bf16x8;
typedef __attribute__((ext_vector_type(4))) float f32x4;
typedef __attribute__((ext_vector_type(4))) int   i32x4;

__device__ __forceinline__ int ch_idx(int b, int i, int j, int n) {
    return (((b*LL + i)*(LL+1) + j)*NNT + n);
}
__device__ __forceinline__ unsigned short f2bf(float x) {
    unsigned u = __float_as_uint(x);
    u = (u + 0x7fffu + ((u >> 16) & 1u)) >> 16;   // RNE
    return (unsigned short)u;
}
// EU/EV slab addressing (shorts): [q][r=0..47][k=0..31] bf16, 16B-chunk XOR swizzle
__device__ __forceinline__ int uvt_base(int q, int r, int kc) {
    return q*1536 + ((((r << 2) + kc) ^ (r & 7)) << 3);
}
__device__ __forceinline__ float wavemax(float x) {
    #pragma unroll
    for (int o = 32; o; o >>= 1) x = fmaxf(x, __shfl_xor(x, o));
    return x;
}

// Pack W[a][e] (e = c*48 + b') = clip(binary[a][b'][c]) into MFMA B-frag order
__global__ void wpack_kernel(const float* __restrict__ binary, unsigned short* __restrict__ Wp) {
    int idx = blockIdx.x*256 + threadIdx.x;
    if (idx >= 3*KSTEPS*64*8) return;
    int j  = idx & 7;
    int l  = (idx >> 3) & 63;
    int ks = (idx >> 9) % KSTEPS;
    int nt = idx / (KSTEPS*512);
    int e = ks*32 + ((l >> 4) << 3) + j;
    int n = nt*16 + (l & 15);
    int bp = e % 48, c = e / 48;
    float v = fmaxf(binary[n*N2 + bp*48 + c], EPSV);
    Wp[idx] = f2bf(v);
}

#define MFMA16(A,B,C) __builtin_amdgcn_mfma_f32_16x16x32_bf16(A,B,C,0,0,0)

// issue 16 loads for splits [C*8, C*8+8) (clamped to owned splits)
#define LDCH(U, V, C, TC, UP, VP)                                              \
    { _Pragma("unroll")                                                        \
      for (int dt = 0; dt < 8; ++dt) {                                         \
          int t = (C)*8 + dt; int tt = (t < (TC)) ? t : (TC)-1;                \
          int kk = rr + tt*wpi;                                                \
          U[dt] = (UP)[kk*NNT + ln]; V[dt] = (VP)[kk*CH_J + ln];               \
      } }

// consume chunk: exp with per-split two-sided shift (args <= 0), b128 slab write
#define CONSCH(U, V, C, II, TC, MW)                                            \
    { int pu[4], pv[4];                                                        \
      _Pragma("unroll")                                                        \
      for (int dt = 0; dt < 8; ++dt) {                                         \
          int t = (C)*8 + dt; int tt = (t < (TC)) ? t : (TC)-1;                \
          int kk = rr + tt*wpi;                                                \
          float al = cmax[(II)*33 + (II) + 1 + kk];                            \
          unsigned eu = f2bf(__expf(U[dt] - al));                              \
          unsigned ev = f2bf(__expf(V[dt] + al - (MW)));                       \
          if (dt & 1) { pu[dt>>1] |= (int)(eu << 16); pv[dt>>1] |= (int)(ev << 16); } \
          else        { pu[dt>>1]  = (int)eu;         pv[dt>>1]  = (int)ev; }  \
      }                                                                        \
      if (lane < NNT) {                                                        \
          int ad = uvt_base(w, lane, (C));                                     \
          *(i32x4*)&sUV[ad]         = (i32x4){pu[0], pu[1], pu[2], pu[3]};     \
          *(i32x4*)&sUV[12288 + ad] = (i32x4){pv[0], pv[1], pv[2], pv[3]};     \
      } }

// full per-instance stage-1: pipelined loads, mw, slabs, 9 MFMA partial-E
#define STAGE1(EA, II, TC, MWVAR)                                              \
    { const float* up = chart + ch_idx(b, (II), (II)+1, 0);                    \
      const float* vp = chart + ch_idx(b, (II)+1, (II)+s, 0);                  \
      int nch = ((TC) + 7) >> 3;                                               \
      LDCH(ubufA, vbufA, 0, (TC), up, vp)                                      \
      for (int t = 0; t < (TC); ++t) {                                         \
          int kk = rr + t*wpi;                                                 \
          MWVAR = fmaxf(MWVAR, cmax[(II)*33 + (II)+1+kk]                       \
                              + cmax[((II)+1+kk)*33 + (II)+s]);                \
      }                                                                        \
      if (nch > 1) { LDCH(ubufB, vbufB, 1, (TC), up, vp) }                     \
      CONSCH(ubufA, vbufA, 0, (II), (TC), MWVAR)                               \
      if (nch > 1) {                                                           \
          if (nch > 2) { LDCH(ubufA, vbufA, 2, (TC), up, vp) }                 \
          CONSCH(ubufB, vbufB, 1, (II), (TC), MWVAR)                           \
          if (nch > 2) {                                                       \
              if (nch > 3) { LDCH(ubufB, vbufB, 3, (TC), up, vp) }             \
              CONSCH(ubufA, vbufA, 2, (II), (TC), MWVAR)                       \
              if (nch > 3) { CONSCH(ubufB, vbufB, 3, (II), (TC), MWVAR) }      \
          }                                                                    \
      }                                                                        \
      bf16x8 A0 = *(const bf16x8*)&sUV[uvt_base(w,  0 + fr, kg)];              \
      bf16x8 A1 = *(const bf16x8*)&sUV[uvt_base(w, 16 + fr, kg)];              \
      bf16x8 A2 = *(const bf16x8*)&sUV[uvt_base(w, 32 + fr, kg)];              \
      _Pragma("unroll")                                                        \
      for (int jj = 0; jj < 8; ++jj)                                           \
          if (kg*8 + jj >= (TC)) { A0[jj] = 0; A1[jj] = 0; A2[jj] = 0; }       \
      bf16x8 B0 = *(const bf16x8*)&sUV[12288 + uvt_base(w,  0 + fr, kg)];      \
      bf16x8 B1 = *(const bf16x8*)&sUV[12288 + uvt_base(w, 16 + fr, kg)];      \
      bf16x8 B2 = *(const bf16x8*)&sUV[12288 + uvt_base(w, 32 + fr, kg)];      \
      EA[0] = MFMA16(A0,B0,EA[0]); EA[1] = MFMA16(A0,B1,EA[1]); EA[2] = MFMA16(A0,B2,EA[2]); \
      EA[3] = MFMA16(A1,B0,EA[3]); EA[4] = MFMA16(A1,B1,EA[4]); EA[5] = MFMA16(A1,B2,EA[5]); \
      EA[6] = MFMA16(A2,B0,EA[6]); EA[7] = MFMA16(A2,B1,EA[7]); EA[8] = MFMA16(A2,B2,EA[8]); }

#define PACKROW(EA, ROW, SCL)                                                  \
    { float scl_ = (SCL);                                                      \
      _Pragma("unroll")                                                        \
      for (int mt = 0; mt < 3; ++mt) {                                         \
          _Pragma("unroll")                                                    \
          for (int ct = 0; ct < 3; ++ct) {                                     \
              f32x4 d = EA[mt*3 + ct];                                         \
              int e0 = (ct*16 + fr)*48 + mt*16 + kg*4;                         \
              unsigned long long lo = (unsigned long long)f2bf(d[0]*scl_)      \
                                    | ((unsigned long long)f2bf(d[1]*scl_) << 16); \
              unsigned long long hi = (unsigned long long)f2bf(d[2]*scl_)      \
                                    | ((unsigned long long)f2bf(d[3]*scl_) << 16); \
              *(unsigned long long*)&sEb[(ROW)*SEB_S + e0] = lo | (hi << 32);  \
          } } }

// One persistent block (512 thr, 8 waves) per batch element; 31 levels serial.
// Wide levels (pos>8): 16 instances/pass, each wave builds rows w (slot A) and
// w+8 (slot B), slab region reused in-order. Deep levels: R7's WPI split mode.
__global__ __launch_bounds__(512, 2) void inside_kernel(
        const unsigned short* __restrict__ Wp,
        const int* __restrict__ tokens,
        const float* __restrict__ lexical,
        float* __restrict__ chart,
        float* __restrict__ out, int T) {
    const int b = blockIdx.x;
    const int tid = threadIdx.x, lane = tid & 63, w = tid >> 6;
    const int fr = lane & 15, kg = lane >> 4;
    const int ln = (lane < NNT) ? lane : 0;

    __shared__ __align__(16) short sUV[24576];       // EU | EV(+12288)  48 KB
    __shared__ __align__(16) short sEb[16*SEB_S];    // 16 GEMM rows    74.5 KB
    __shared__ float pD[8*PD_S];                     //                 25.3 KB
    __shared__ float cmax[LL*33 + 33];               // row maxima       4.3 KB
    __shared__ float sM[16];

    for (int x = tid; x < 12288; x += 512) ((int*)sUV)[x] = 0;

    for (int row = w; row < LL; row += 8) {
        int tok = tokens[b*LL + row];
        float val = (lane < NNT)
            ? __logf(fmaxf(lexical[(size_t)lane*(size_t)T + (size_t)tok], EPSV))
            : -INFINITY;
        float rm = wavemax(val);
        if (lane < NNT) chart[ch_idx(b, row, row+1, lane)] = val;
        if (lane == 0) cmax[row*33 + row + 1] = rm;
    }
    __syncthreads();

    const bf16x8* wp8 = (const bf16x8*)Wp;
    const int kstart = 9*w;
    float ubufA[8], vbufA[8], ubufB[8], vbufB[8];

    for (int s = 2; s <= LL; ++s) {
        const int pos = LL + 1 - s, nk = s - 1;
        const bool wide = (pos > 8);
        int IPBe, wpi, qA, rr;
        if (wide) { IPBe = 16; wpi = 1; qA = w; rr = 0; }
        else {
            int IPB = 1, ish = 0;
            while (IPB < pos) { IPB <<= 1; ++ish; }     // pos<=8 -> IPB<=8
            int wsh = 3 - ish;
            IPBe = IPB; wpi = 1 << wsh; qA = w >> wsh; rr = w & (wpi - 1);
        }
        const int P = (pos + IPBe - 1)/IPBe;

        for (int p = 0; p < P; ++p) {
            f32x4 eaA[9], eaB[9];
            #pragma unroll
            for (int z = 0; z < 9; ++z) {
                eaA[z] = (f32x4){0.f,0.f,0.f,0.f};
                eaB[z] = (f32x4){0.f,0.f,0.f,0.f};
            }

            // ---- slot A
            const int iA = p*IPBe + qA;
            int tcA = 0; float mwA = -INFINITY;
            if (iA < pos && rr < nk) tcA = (nk - 1 - rr)/wpi + 1;
            if (tcA > 0) STAGE1(eaA, iA, tcA, mwA);
            if (lane == 0) sM[w] = mwA;
            if (wide) PACKROW(eaA, w, (tcA > 0) ? 1.f : 0.f);

            // Wp prefetch chunk A (ksteps kstart..kstart+4)
            bf16x8 wAf[5][3];
            #pragma unroll
            for (int t = 0; t < 5; ++t) {
                #pragma unroll
                for (int nt = 0; nt < 3; ++nt)
                    wAf[t][nt] = wp8[(nt*KSTEPS + kstart + t)*64 + lane];
            }

            // ---- slot B (wide only)
            if (wide) {
                const int iB = p*16 + 8 + w;
                int tcB = 0; float mwB = -INFINITY;
                if (iB < pos) tcB = nk;
                if (tcB > 0) STAGE1(eaB, iB, tcB, mwB);
                if (lane == 0) sM[8 + w] = mwB;
                PACKROW(eaB, 8 + w, (tcB > 0) ? 1.f : 0.f);
            }

            // Wp prefetch chunk B (ksteps kstart+5..kstart+8)
            bf16x8 wBf[4][3];
            #pragma unroll
            for (int t = 0; t < 4; ++t) {
                #pragma unroll
                for (int nt = 0; nt < 3; ++nt)
                    wBf[t][nt] = wp8[(nt*KSTEPS + kstart + 5 + t)*64 + lane];
            }

            if (!wide) {
                __syncthreads();   // B1 (deep only: sM needed for cross-wave M)
                int bse = w & ~(wpi - 1);
                float MA = sM[bse];
                #pragma unroll
                for (int t = 1; t < 8; ++t) if (t < wpi) MA = fmaxf(MA, sM[bse + t]);
                float sA = (mwA > -INFINITY) ? __expf(mwA - MA) : 0.f;
                PACKROW(eaA, w, sA);
                PACKROW(eaB, 8 + w, 0.f);
            }
            __syncthreads();   // B2: sEb (and sM) ready

            // ---- stage-2: K-split MFMA GEMM [16 x 2304] x [2304 x 48]
            {
                f32x4 c0 = {0.f,0.f,0.f,0.f}, c1 = c0, c2 = c0;
                #pragma unroll
                for (int t = 0; t < 9; ++t) {
                    int ks = kstart + t;
                    bf16x8 af = *(const bf16x8*)&sEb[fr*SEB_S + ks*32 + kg*8];
                    bf16x8 q0, q1, q2;
                    if (t < 5) { q0 = wAf[t][0];   q1 = wAf[t][1];   q2 = wAf[t][2]; }
                    else       { q0 = wBf[t-5][0]; q1 = wBf[t-5][1]; q2 = wBf[t-5][2]; }
                    c0 = MFMA16(af, q0, c0);
                    c1 = MFMA16(af, q1, c1);
                    c2 = MFMA16(af, q2, c2);
                }
                #pragma unroll
                for (int r2 = 0; r2 < 4; ++r2) {
                    int row = kg*4 + r2;
                    pD[w*PD_S + 0*PD_NT + row*16 + fr] = c0[r2];
                    pD[w*PD_S + 1*PD_NT + row*16 + fr] = c1[r2];
                    pD[w*PD_S + 2*PD_NT + row*16 + fr] = c2[r2];
                }
            }
            __syncthreads();   // B3

            // ---- epilogue
            const int nn = ln;
            if (wide) {
                int i2 = p*16 + w;
                if (i2 < pos) {
                    float sum = 0.f;
                    #pragma unroll
                    for (int w2 = 0; w2 < 8; ++w2)
                        sum += pD[w2*PD_S + (nn >> 4)*PD_NT + w*16 + (nn & 15)];
                    float val = sM[w] + __logf(sum);
                    float rm = wavemax((lane < NNT) ? val : -INFINITY);
                    if (lane < NNT) chart[ch_idx(b, i2, i2 + s, lane)] = val;
                    if (lane == 0) cmax[i2*33 + i2 + s] = rm;
                }
                int i3 = p*16 + 8 + w;
                if (i3 < pos) {
                    float sum = 0.f;
                    #pragma unroll
                    for (int w2 = 0; w2 < 8; ++w2)
                        sum += pD[w2*PD_S + (nn >> 4)*PD_NT + (8 + w)*16 + (nn & 15)];
                    float val = sM[8 + w] + __logf(sum);
                    float rm = wavemax((lane < NNT) ? val : -INFINITY);
                    if (lane < NNT) chart[ch_idx(b, i3, i3 + s, lane)] = val;
                    if (lane == 0) cmax[i3*33 + i3 + s] = rm;
                }
            } else {
                if (w < IPBe) {
                    int i2 = p*IPBe + w;
                    if (i2 < pos) {
                        int bse = w*wpi;
                        float Mq = sM[bse];
                        #pragma unroll
                        for (int t = 1; t < 8; ++t) if (t < wpi) Mq = fmaxf(Mq, sM[bse + t]);
                        float sum = 0.f;
                        #pragma unroll
                        for (int w2 = 0; w2 < 8; ++w2) {
                            const float* pp = &pD[w2*PD_S + (nn >> 4)*PD_NT + (nn & 15)];
                            #pragma unroll
                            for (int t = 0; t < 8; ++t)
                                if (t < wpi) sum += pp[(bse + t)*16];
                        }
                        float val = Mq + __logf(sum);
                        float rm = wavemax((lane < NNT) ? val : -INFINITY);
                        if (lane < NNT) chart[ch_idx(b, i2, i2 + s, lane)] = val;
                        if (lane == 0) {
                            cmax[i2*33 + i2 + s] = rm;
                            if (s == LL) out[b] = val;
                        }
                    }
                }
            }
            __syncthreads();   // B4
        }
    }
}

extern "C" void kernel_launch(void* const* d_in, const int* in_sizes, int n_in,
                              void* d_out, int out_size, void* d_ws, size_t ws_size,
                              hipStream_t stream) {
    const int*   tokens  = (const int*)d_in[0];
    const float* binary  = (const float*)d_in[1];
    const float* lexical = (const float*)d_in[2];
    float* out = (float*)d_out;

    float* chart = (float*)d_ws;                                   // 6.49 MB
    unsigned short* Wp = (unsigned short*)(chart + (size_t)BB*LL*(LL+1)*NNT);  // 221 KB bf16

    int T = in_sizes[2] / NNT;   // 32000

    wpack_kernel<<<(3*KSTEPS*64*8 + 255)/256, 256, 0, stream>>>(binary, Wp);
    inside_kernel<<<BB, 512, 0, stream>>>(Wp, tokens, lexical, chart, out, T);
}

// Round 9
// 279.636 us; speedup vs baseline: 1.8812x; 1.8812x over previous
//
#include <hip/hip_runtime.h>
#include <math.h>

#define NNT 48
#define LL 32
#define BB 32
#define N2 2304            // 48*48
#define KSTEPS 72          // 2304/32
#define EPSV 1e-30f
#define CH_J ((LL+1)*NNT)  // 1584
#define SEB_S 2328         // shorts per sEb row (2304 + pad)
#define PD_NT 264          // floats per nt-tile in pD
#define PD_S  (3*PD_NT)    // 792

typedef __attribute__((ext_vector_type(8))) short bf16x8;
typedef __attribute__((ext_vector_type(4))) float f32x4;
typedef __attribute__((ext_vector_type(4))) int   i32x4;

__device__ __forceinline__ int ch_idx(int b, int i, int j, int n) {
    return (((b*LL + i)*(LL+1) + j)*NNT + n);
}
__device__ __forceinline__ unsigned short f2bf(float x) {
    unsigned u = __float_as_uint(x);
    u = (u + 0x7fffu + ((u >> 16) & 1u)) >> 16;   // RNE
    return (unsigned short)u;
}
// EU/EV slab addressing (shorts): [q][r=0..47][k=0..31] bf16, 16B-chunk XOR swizzle
__device__ __forceinline__ int uvt_base(int q, int r, int kc) {
    return q*1536 + ((((r << 2) + kc) ^ (r & 7)) << 3);
}
__device__ __forceinline__ float wavemax(float x) {
    #pragma unroll
    for (int o = 32; o; o >>= 1) x = fmaxf(x, __shfl_xor(x, o));
    return x;
}

// prep: blocks 0..431 pack W into MFMA B-frag order (e = c*48+b'); blocks
// 432..687 write leaf chart rows + their row-max into the chart j=0 column.
__global__ void prep_kernel(const float* __restrict__ binary, const int* __restrict__ tokens,
                            const float* __restrict__ lexical, unsigned short* __restrict__ Wp,
                            float* __restrict__ chart, int T) {
    if (blockIdx.x < 432) {
        int idx = blockIdx.x*256 + threadIdx.x;   // 432*256 == 3*72*512 exactly
        int j  = idx & 7;
        int l  = (idx >> 3) & 63;
        int ks = (idx >> 9) % KSTEPS;
        int nt = idx / (KSTEPS*512);
        int e = ks*32 + ((l >> 4) << 3) + j;
        int n = nt*16 + (l & 15);
        int bp = e % 48, c = e / 48;
        Wp[idx] = f2bf(fmaxf(binary[n*N2 + bp*48 + c], EPSV));
    } else {
        int row = (blockIdx.x - 432)*4 + (threadIdx.x >> 6);   // 1024 rows
        int lane = threadIdx.x & 63;
        int b = row >> 5, i = row & 31;
        int tok = tokens[b*LL + i];
        float val = (lane < NNT)
            ? __logf(fmaxf(lexical[(size_t)lane*(size_t)T + (size_t)tok], EPSV))
            : -INFINITY;
        float rm = wavemax(val);
        if (lane < NNT) chart[ch_idx(b, i, i+1, lane)] = val;
        if (lane == 0) chart[ch_idx(b, i, 0, i+1)] = rm;   // rmax cache
    }
}

#define MFMA16(A,B,C) __builtin_amdgcn_mfma_f32_16x16x32_bf16(A,B,C,0,0,0)

// issue 16 loads for split-slots [C*8, C*8+8) (clamped to owned splits)
#define LDCH(U, V, C, TC, UP, VP)                                              \
    { _Pragma("unroll")                                                        \
      for (int dt = 0; dt < 8; ++dt) {                                         \
          int t = (C)*8 + dt; int tt = (t < (TC)) ? t : (TC)-1;                \
          int kk = rr + tt*wpi;                                                \
          U[dt] = (UP)[kk*NNT + ln]; V[dt] = (VP)[kk*CH_J + ln];               \
      } }

// consume chunk: per-split two-sided shift (args <= 0 -> overflow-free), b128 write
#define CONSCH(U, V, C, TC, MM, SL)                                            \
    { int pu[4], pv[4];                                                        \
      _Pragma("unroll")                                                        \
      for (int dt = 0; dt < 8; ++dt) {                                         \
          int t = (C)*8 + dt; int tt = (t < (TC)) ? t : (TC)-1;                \
          int kk = rr + tt*wpi;                                                \
          float al = sAl[w][SL][kk];                                           \
          unsigned eu = f2bf(__expf(U[dt] - al));                              \
          unsigned ev = f2bf(__expf(V[dt] + al - (MM)));                       \
          if (dt & 1) { pu[dt>>1] |= (int)(eu << 16); pv[dt>>1] |= (int)(ev << 16); } \
          else        { pu[dt>>1]  = (int)eu;         pv[dt>>1]  = (int)ev; }  \
      }                                                                        \
      if (lane < NNT) {                                                        \
          int ad = uvt_base(w, lane, (C));                                     \
          *(i32x4*)&sUV[ad]         = (i32x4){pu[0], pu[1], pu[2], pu[3]};     \
          *(i32x4*)&sUV[12288 + ad] = (i32x4){pv[0], pv[1], pv[2], pv[3]};     \
      } }

// per-instance stage-1: pipelined loads, slabs, 9 MFMA partial-E (A-frag masked
// past TC -> stale slab chunks are harmless: finite * 0)
#define STAGE1(EA, II0, BB0, TC, MM, SL)                                       \
    { const float* up = chart + ch_idx((BB0), (II0), (II0)+1, 0);              \
      const float* vp = chart + ch_idx((BB0), (II0)+1, (II0)+s, 0);            \
      int nch = ((TC) + 7) >> 3;                                               \
      LDCH(ubufA, vbufA, 0, (TC), up, vp)                                      \
      if (nch > 1) { LDCH(ubufB, vbufB, 1, (TC), up, vp) }                     \
      CONSCH(ubufA, vbufA, 0, (TC), MM, SL)                                    \
      if (nch > 1) {                                                           \
          if (nch > 2) { LDCH(ubufA, vbufA, 2, (TC), up, vp) }                 \
          CONSCH(ubufB, vbufB, 1, (TC), MM, SL)                                \
          if (nch > 2) {                                                       \
              if (nch > 3) { LDCH(ubufB, vbufB, 3, (TC), up, vp) }             \
              CONSCH(ubufA, vbufA, 2, (TC), MM, SL)                            \
              if (nch > 3) { CONSCH(ubufB, vbufB, 3, (TC), MM, SL) }           \
          }                                                                    \
      }                                                                        \
      bf16x8 A0 = *(const bf16x8*)&sUV[uvt_base(w,  0 + fr, kg)];              \
      bf16x8 A1 = *(const bf16x8*)&sUV[uvt_base(w, 16 + fr, kg)];              \
      bf16x8 A2 = *(const bf16x8*)&sUV[uvt_base(w, 32 + fr, kg)];              \
      _Pragma("unroll")                                                        \
      for (int jj = 0; jj < 8; ++jj)                                           \
          if (kg*8 + jj >= (TC)) { A0[jj] = 0; A1[jj] = 0; A2[jj] = 0; }       \
      bf16x8 B0 = *(const bf16x8*)&sUV[12288 + uvt_base(w,  0 + fr, kg)];      \
      bf16x8 B1 = *(const bf16x8*)&sUV[12288 + uvt_base(w, 16 + fr, kg)];      \
      bf16x8 B2 = *(const bf16x8*)&sUV[12288 + uvt_base(w, 32 + fr, kg)];      \
      EA[0] = MFMA16(A0,B0,EA[0]); EA[1] = MFMA16(A0,B1,EA[1]); EA[2] = MFMA16(A0,B2,EA[2]); \
      EA[3] = MFMA16(A1,B0,EA[3]); EA[4] = MFMA16(A1,B1,EA[4]); EA[5] = MFMA16(A1,B2,EA[5]); \
      EA[6] = MFMA16(A2,B0,EA[6]); EA[7] = MFMA16(A2,B1,EA[7]); EA[8] = MFMA16(A2,B2,EA[8]); }

#define PACKROW(EA, ROW)                                                       \
    { _Pragma("unroll")                                                        \
      for (int mt = 0; mt < 3; ++mt) {                                         \
          _Pragma("unroll")                                                    \
          for (int ct = 0; ct < 3; ++ct) {                                     \
              f32x4 d = EA[mt*3 + ct];                                         \
              int e0 = (ct*16 + fr)*48 + mt*16 + kg*4;                         \
              unsigned long long lo = (unsigned long long)f2bf(d[0])           \
                                    | ((unsigned long long)f2bf(d[1]) << 16);  \
              unsigned long long hi = (unsigned long long)f2bf(d[2])           \
                                    | ((unsigned long long)f2bf(d[3]) << 16);  \
              *(unsigned long long*)&sEb[(ROW)*SEB_S + e0] = lo | (hi << 32);  \
          } } }

#define PACKZERO(ROW)                                                          \
    { _Pragma("unroll")                                                        \
      for (int mt = 0; mt < 3; ++mt) {                                         \
          _Pragma("unroll")                                                    \
          for (int ct = 0; ct < 3; ++ct) {                                     \
              int e0 = (ct*16 + fr)*48 + mt*16 + kg*4;                         \
              *(unsigned long long*)&sEb[(ROW)*SEB_S + e0] = 0ull;             \
          } } }

// DEEP=0 (s<=25): 16 instances/block (2 per wave), grid 2*pos. Straight-line,
// 2 barriers. DEEP=1 (s>=26): 1 instance/block, grid 32*pos, 8-way split-
// parallel; M is instance-global (all waves compute it identically), scl=1.
template<int DEEP>
__global__ __launch_bounds__(512) void level_kernel(const unsigned short* __restrict__ Wp,
                                                    float* __restrict__ chart,
                                                    float* __restrict__ out,
                                                    int s, int pos) {
    const int tid = threadIdx.x, lane = tid & 63, w = tid >> 6;
    const int fr = lane & 15, kg = lane >> 4;
    const int ln = (lane < NNT) ? lane : 0;
    const int nk = s - 1;
    const int rr = DEEP ? w : 0;
    const int wpi = DEEP ? 8 : 1;

    __shared__ __align__(16) short sUV[24576];       // EU | EV(+12288)  48 KB
    __shared__ __align__(16) short sEb[16*SEB_S];    //                 74.5 KB
    __shared__ float pD[8*PD_S];                     //                 24.8 KB
    __shared__ float sAl[8][2][32];                  // per-wave per-slot alpha

    int b0, i0, b1 = 0, i1 = 0;
    if (DEEP) {
        int g = blockIdx.x; b0 = g/pos; i0 = g - b0*pos;
    } else {
        int g0 = blockIdx.x*16 + w, g1 = g0 + 8;
        b0 = g0/pos; i0 = g0 - b0*pos;
        b1 = g1/pos; i1 = g1 - b1*pos;
    }

    // ---- M phase: lane t = split t; alpha/beta from the chart j=0 rmax column
    float MA, MB = -INFINITY;
    {
        float alA = -INFINITY, btA = -INFINITY, alB = -INFINITY, btB = -INFINITY;
        if (lane < nk) {
            alA = chart[ch_idx(b0, i0, 0, i0 + 1 + lane)];
            btA = chart[ch_idx(b0, i0 + 1 + lane, 0, i0 + s)];
            if (!DEEP) {
                alB = chart[ch_idx(b1, i1, 0, i1 + 1 + lane)];
                btB = chart[ch_idx(b1, i1 + 1 + lane, 0, i1 + s)];
            }
        }
        if (lane < 32) {
            sAl[w][0][lane] = alA;
            if (!DEEP) sAl[w][1][lane] = alB;
        }
        MA = wavemax((lane < nk) ? alA + btA : -INFINITY);
        if (!DEEP) MB = wavemax((lane < nk) ? alB + btB : -INFINITY);
    }

    // ---- stage-1
    float ubufA[8], vbufA[8], ubufB[8], vbufB[8];
    const int tcA = DEEP ? ((nk - 1 - w)/8 + 1) : nk;
    {
        f32x4 ea[9];
        #pragma unroll
        for (int z = 0; z < 9; ++z) ea[z] = (f32x4){0.f, 0.f, 0.f, 0.f};
        STAGE1(ea, i0, b0, tcA, MA, 0)
        PACKROW(ea, w)
    }
    if (DEEP) {
        PACKZERO(8 + w)
    } else {
        f32x4 ea[9];
        #pragma unroll
        for (int z = 0; z < 9; ++z) ea[z] = (f32x4){0.f, 0.f, 0.f, 0.f};
        STAGE1(ea, i1, b1, nk, MB, 1)
        PACKROW(ea, 8 + w)
    }

    // ---- small Wp prefetch (3 ksteps, 36 VGPR) — rest loads inline
    const bf16x8* wp8 = (const bf16x8*)Wp;
    const int kstart = 9*w;
    bf16x8 wPf[3][3];
    #pragma unroll
    for (int t = 0; t < 3; ++t)
        #pragma unroll
        for (int nt = 0; nt < 3; ++nt)
            wPf[t][nt] = wp8[(nt*KSTEPS + kstart + t)*64 + lane];

    __syncthreads();   // B2: sEb ready

    // ---- stage-2: K-split MFMA GEMM [16 x 2304] x [2304 x 48]
    {
        f32x4 c0 = {0.f,0.f,0.f,0.f}, c1 = c0, c2 = c0;
        #pragma unroll
        for (int t = 0; t < 9; ++t) {
            int ks = kstart + t;
            bf16x8 af = *(const bf16x8*)&sEb[fr*SEB_S + ks*32 + kg*8];
            bf16x8 q0 = (t < 3) ? wPf[t][0] : wp8[(0*KSTEPS + ks)*64 + lane];
            bf16x8 q1 = (t < 3) ? wPf[t][1] : wp8[(1*KSTEPS + ks)*64 + lane];
            bf16x8 q2 = (t < 3) ? wPf[t][2] : wp8[(2*KSTEPS + ks)*64 + lane];
            c0 = MFMA16(af, q0, c0);
            c1 = MFMA16(af, q1, c1);
            c2 = MFMA16(af, q2, c2);
        }
        #pragma unroll
        for (int r2 = 0; r2 < 4; ++r2) {
            int row = kg*4 + r2;
            pD[w*PD_S + 0*PD_NT + row*16 + fr] = c0[r2];
            pD[w*PD_S + 1*PD_NT + row*16 + fr] = c1[r2];
            pD[w*PD_S + 2*PD_NT + row*16 + fr] = c2[r2];
        }
    }
    __syncthreads();   // B3

    // ---- epilogue: val = M + log(sum); store chart + rmax (j=0 column)
    if (DEEP) {
        if (w == 0) {
            float sum = 0.f;
            #pragma unroll
            for (int row = 0; row < 8; ++row)
                #pragma unroll
                for (int w2 = 0; w2 < 8; ++w2)
                    sum += pD[w2*PD_S + (ln >> 4)*PD_NT + row*16 + (ln & 15)];
            float val = MA + __logf(sum);
            float rm = wavemax((lane < NNT) ? val : -INFINITY);
            if (lane < NNT) chart[ch_idx(b0, i0, i0 + s, lane)] = val;
            if (lane == 0) {
                chart[ch_idx(b0, i0, 0, i0 + s)] = rm;
                if (s == LL) out[b0] = val;
            }
        }
    } else {
        {
            float sum = 0.f;
            #pragma unroll
            for (int w2 = 0; w2 < 8; ++w2)
                sum += pD[w2*PD_S + (ln >> 4)*PD_NT + w*16 + (ln & 15)];
            float val = MA + __logf(sum);
            float rm = wavemax((lane < NNT) ? val : -INFINITY);
            if (lane < NNT) chart[ch_idx(b0, i0, i0 + s, lane)] = val;
            if (lane == 0) chart[ch_idx(b0, i0, 0, i0 + s)] = rm;
        }
        {
            float sum = 0.f;
            #pragma unroll
            for (int w2 = 0; w2 < 8; ++w2)
                sum += pD[w2*PD_S + (ln >> 4)*PD_NT + (8 + w)*16 + (ln & 15)];
            float val = MB + __logf(sum);
            float rm = wavemax((lane < NNT) ? val : -INFINITY);
            if (lane < NNT) chart[ch_idx(b1, i1, i1 + s, lane)] = val;
            if (lane == 0) chart[ch_idx(b1, i1, 0, i1 + s)] = rm;
        }
    }
}

extern "C" void kernel_launch(void* const* d_in, const int* in_sizes, int n_in,
                              void* d_out, int out_size, void* d_ws, size_t ws_size,
                              hipStream_t stream) {
    const int*   tokens  = (const int*)d_in[0];
    const float* binary  = (const float*)d_in[1];
    const float* lexical = (const float*)d_in[2];
    float* out = (float*)d_out;

    float* chart = (float*)d_ws;                                   // 6.49 MB
    unsigned short* Wp = (unsigned short*)(chart + (size_t)BB*LL*(LL+1)*NNT);  // 221 KB bf16

    int T = in_sizes[2] / NNT;   // 32000

    prep_kernel<<<688, 256, 0, stream>>>(binary, tokens, lexical, Wp, chart, T);

    for (int s = 2; s <= LL; ++s) {
        int pos = LL + 1 - s;
        if (s <= 25) level_kernel<0><<<2*pos, 512, 0, stream>>>(Wp, chart, out, s, pos);
        else         level_kernel<1><<<32*pos, 512, 0, stream>>>(Wp, chart, out, s, pos);
    }
}